// Round 1
// baseline (2080.010 us; speedup 1.0000x reference)
//
#include <hip/hip_runtime.h>
#include <math.h>

#define NATOMS 20000
#define NEDGES 400000
#define EMBD   256
#define NRBF   50
#define NGATE  10
#define FOUT   128
#define EPB    256     // edges per block in main kernel
#define OUTERC 5.0f

// RBF constants: offset_j = j*(5/49), coeff = -0.5/(5/49)^2, folded log2(e) for exp2
#define RBF_D   (5.0f/49.0f)
#define RBF_C2  (-0.5f*(49.0f/5.0f)*(49.0f/5.0f)*1.4426950408889634f)
#define PI_OVER_OUTER 0.62831853071795864769f

static __device__ __forceinline__ float softplusf(float x){
    return (x > 15.0f) ? x : log1pf(__expf(x));
}

// ---------------- precompute 1: E1i,E1j,A1,u1,M0,M1 + edge counting ----------------
// E1i = emb@Wai + bai [100,256]; E1j = emb@Waj + baj
// A1  = Wd@Wdt [50,256]; u1 = bd@Wdt [256]
// M0  = Wgam0@Wexp0 [256,128]; M1 = Wgam0@Wexp1
__global__ __launch_bounds__(256) void k_pre1(
    const float* __restrict__ emb, const float* __restrict__ Wai, const float* __restrict__ bai,
    const float* __restrict__ Waj, const float* __restrict__ baj, const float* __restrict__ Wd,
    const float* __restrict__ Wdt, const float* __restrict__ bd, const float* __restrict__ Wgam,
    const float* __restrict__ Wexp, const int* __restrict__ esrc,
    int* __restrict__ counts,
    float* __restrict__ E1i, float* __restrict__ E1j, float* __restrict__ A1,
    float* __restrict__ u1, float* __restrict__ M0, float* __restrict__ M1)
{
    long long gid = (long long)blockIdx.x * 256 + threadIdx.x;
    if (gid < 25600) {
        int m = (int)gid / 256, n = (int)gid % 256;
        float s = bai[n];
        for (int k = 0; k < EMBD; k++) s += emb[m*EMBD+k] * Wai[k*EMBD+n];
        E1i[gid] = s;
    } else if (gid < 51200) {
        int g = (int)gid - 25600; int m = g/256, n = g%256;
        float s = baj[n];
        for (int k = 0; k < EMBD; k++) s += emb[m*EMBD+k] * Waj[k*EMBD+n];
        E1j[g] = s;
    } else if (gid < 64000) {
        int g = (int)gid - 51200; int m = g/256, n = g%256;
        float s = 0.f;
        for (int k = 0; k < EMBD; k++) s += Wd[m*EMBD+k] * Wdt[k*EMBD+n];
        A1[g] = s;
    } else if (gid < 64256) {
        int n = (int)gid - 64000;
        float s = 0.f;
        for (int k = 0; k < EMBD; k++) s += bd[k] * Wdt[k*EMBD+n];
        u1[n] = s;
    } else if (gid < 97024) {
        int g = (int)gid - 64256; int m = g/128, n = g%128;
        float s = 0.f;
        for (int k = 0; k < EMBD; k++) s += Wgam[m*EMBD+k] * Wexp[k*FOUT+n];
        M0[g] = s;
    } else if (gid < 129792) {
        int g = (int)gid - 97024; int m = g/128, n = g%128;
        const float* W1 = Wexp + EMBD*FOUT;
        float s = 0.f;
        for (int k = 0; k < EMBD; k++) s += Wgam[m*EMBD+k] * W1[k*FOUT+n];
        M1[g] = s;
    } else {
        long long e = gid - 129792;
        if (e < NEDGES) atomicAdd(&counts[esrc[e]], 1);
    }
}

// ---------------- precompute 2: E2i,E2j,R0,R1,Qg,Qn,sv + prefix scan ----------------
// E2i = E1i@Wgam1 [100,256]; E2j = E1j@Wgam2
// R0 = A1@M0 [50,128]; R1 = A1@M1
// Qg = A1@W_g [50,10]; Qn = A1@W_noise
// sv: [0..127]=s0=u1@M0, [128..255]=s1, [256..383]=d0=bdt@M0+bgam@Wexp0+bexp0,
//     [384..511]=d1, [512..521]=gc1=u1@Wg, [522..531]=gc2=bdt@Wg, [532..541]=nc1, [542..551]=nc2
#define P2_MM_THREADS 65552
#define P2_MM_BLOCKS  257
__global__ __launch_bounds__(256) void k_pre2(
    const float* __restrict__ Wgam, const float* __restrict__ Wg, const float* __restrict__ Wn,
    const float* __restrict__ bdt, const float* __restrict__ bgam,
    const float* __restrict__ Wexp, const float* __restrict__ bexp,
    const float* __restrict__ E1i, const float* __restrict__ E1j,
    const float* __restrict__ A1, const float* __restrict__ u1,
    const float* __restrict__ M0, const float* __restrict__ M1,
    float* __restrict__ E2i, float* __restrict__ E2j,
    float* __restrict__ R0, float* __restrict__ R1,
    float* __restrict__ Qg, float* __restrict__ Qn, float* __restrict__ sv,
    const int* __restrict__ counts, int* __restrict__ cursors)
{
    if (blockIdx.x == P2_MM_BLOCKS) {
        // single-block exclusive scan of counts -> cursors
        __shared__ int part[256];
        int t = threadIdx.x;
        const int CH = (NATOMS + 255) / 256;   // 79
        int base = t * CH;
        int s = 0;
        for (int i = 0; i < CH; i++) { int idx = base + i; if (idx < NATOMS) s += counts[idx]; }
        part[t] = s;
        __syncthreads();
        for (int d = 1; d < 256; d <<= 1) {
            int v = (t >= d) ? part[t - d] : 0;
            __syncthreads();
            part[t] += v;
            __syncthreads();
        }
        int run = (t == 0) ? 0 : part[t - 1];
        for (int i = 0; i < CH; i++) {
            int idx = base + i;
            if (idx < NATOMS) { cursors[idx] = run; run += counts[idx]; }
        }
        return;
    }
    long long gid = (long long)blockIdx.x * 256 + threadIdx.x;
    if (gid >= P2_MM_THREADS) return;
    if (gid < 25600) {
        int m = (int)gid / 256, n = (int)gid % 256;
        const float* Wg1 = Wgam + 256*EMBD;
        float s = 0.f;
        for (int k = 0; k < EMBD; k++) s += E1i[m*EMBD+k] * Wg1[k*EMBD+n];
        E2i[gid] = s;
    } else if (gid < 51200) {
        int g = (int)gid - 25600; int m = g/256, n = g%256;
        const float* Wg2 = Wgam + 512*EMBD;
        float s = 0.f;
        for (int k = 0; k < EMBD; k++) s += E1j[m*EMBD+k] * Wg2[k*EMBD+n];
        E2j[g] = s;
    } else if (gid < 57600) {
        int g = (int)gid - 51200; int m = g/128, n = g%128;
        float s = 0.f;
        for (int k = 0; k < EMBD; k++) s += A1[m*EMBD+k] * M0[k*FOUT+n];
        R0[g] = s;
    } else if (gid < 64000) {
        int g = (int)gid - 57600; int m = g/128, n = g%128;
        float s = 0.f;
        for (int k = 0; k < EMBD; k++) s += A1[m*EMBD+k] * M1[k*FOUT+n];
        R1[g] = s;
    } else if (gid < 64500) {
        int g = (int)gid - 64000; int m = g/10, t = g%10;
        float s = 0.f;
        for (int k = 0; k < EMBD; k++) s += A1[m*EMBD+k] * Wg[k*NGATE+t];
        Qg[g] = s;
    } else if (gid < 65000) {
        int g = (int)gid - 64500; int m = g/10, t = g%10;
        float s = 0.f;
        for (int k = 0; k < EMBD; k++) s += A1[m*EMBD+k] * Wn[k*NGATE+t];
        Qn[g] = s;
    } else {
        int i = (int)gid - 65000;  // < 552
        if (i < 128) {
            float s = 0.f;
            for (int k = 0; k < EMBD; k++) s += u1[k] * M0[k*FOUT+i];
            sv[i] = s;
        } else if (i < 256) {
            int f = i - 128; float s = 0.f;
            for (int k = 0; k < EMBD; k++) s += u1[k] * M1[k*FOUT+f];
            sv[i] = s;
        } else if (i < 384) {
            int f = i - 256; float s = bexp[f];
            for (int k = 0; k < EMBD; k++) s += bdt[k]*M0[k*FOUT+f] + bgam[k]*Wexp[k*FOUT+f];
            sv[i] = s;
        } else if (i < 512) {
            int f = i - 384; float s = bexp[FOUT+f];
            const float* W1 = Wexp + EMBD*FOUT;
            for (int k = 0; k < EMBD; k++) s += bdt[k]*M1[k*FOUT+f] + bgam[k]*W1[k*FOUT+f];
            sv[i] = s;
        } else if (i < 522) {
            int t = i - 512; float s = 0.f;
            for (int k = 0; k < EMBD; k++) s += u1[k] * Wg[k*NGATE+t];
            sv[i] = s;
        } else if (i < 532) {
            int t = i - 522; float s = 0.f;
            for (int k = 0; k < EMBD; k++) s += bdt[k] * Wg[k*NGATE+t];
            sv[i] = s;
        } else if (i < 542) {
            int t = i - 532; float s = 0.f;
            for (int k = 0; k < EMBD; k++) s += u1[k] * Wn[k*NGATE+t];
            sv[i] = s;
        } else {
            int t = i - 542; float s = 0.f;
            for (int k = 0; k < EMBD; k++) s += bdt[k] * Wn[k*NGATE+t];
            sv[i] = s;
        }
    }
}

// ---------------- precompute 3: Ti/Tj tables [100,128] + scatter sort ----------------
#define P3_MM_BLOCKS 200
__global__ __launch_bounds__(256) void k_pre3(
    const float* __restrict__ E2i, const float* __restrict__ E2j,
    const float* __restrict__ Wexp,
    float* __restrict__ Ti0, float* __restrict__ Ti1,
    float* __restrict__ Tj0, float* __restrict__ Tj1,
    const int* __restrict__ esrc, int* __restrict__ cursors, int* __restrict__ sorted)
{
    if (blockIdx.x >= P3_MM_BLOCKS) {
        long long e = (long long)(blockIdx.x - P3_MM_BLOCKS) * 256 + threadIdx.x;
        if (e < NEDGES) {
            int s = esrc[e];
            int p = atomicAdd(&cursors[s], 1);
            sorted[p] = (int)e;
        }
        return;
    }
    int gid = blockIdx.x * 256 + threadIdx.x;   // < 51200
    const float* W1 = Wexp + EMBD*FOUT;
    if (gid < 12800) {
        int m = gid/128, f = gid%128; float s = 0.f;
        for (int k = 0; k < EMBD; k++) s += E2i[m*EMBD+k] * Wexp[k*FOUT+f];
        Ti0[gid] = s;
    } else if (gid < 25600) {
        int g = gid-12800; int m = g/128, f = g%128; float s = 0.f;
        for (int k = 0; k < EMBD; k++) s += E2i[m*EMBD+k] * W1[k*FOUT+f];
        Ti1[g] = s;
    } else if (gid < 38400) {
        int g = gid-25600; int m = g/128, f = g%128; float s = 0.f;
        for (int k = 0; k < EMBD; k++) s += E2j[m*EMBD+k] * Wexp[k*FOUT+f];
        Tj0[g] = s;
    } else {
        int g = gid-38400; int m = g/128, f = g%128; float s = 0.f;
        for (int k = 0; k < EMBD; k++) s += E2j[m*EMBD+k] * W1[k*FOUT+f];
        Tj1[g] = s;
    }
}

// ---------------- main kernel: 256 sorted edges per block, 128 threads ----------------
__global__ __launch_bounds__(128) void k_main(
    const int* __restrict__ z, const int* __restrict__ esrc, const int* __restrict__ edst,
    const float* __restrict__ ew, const float* __restrict__ evec, const float* __restrict__ noise,
    const int* __restrict__ sorted,
    const float* __restrict__ R0, const float* __restrict__ R1,
    const float* __restrict__ Qg, const float* __restrict__ Qn,
    const float* __restrict__ Ti0, const float* __restrict__ Ti1,
    const float* __restrict__ Tj0, const float* __restrict__ Tj1,
    const float* __restrict__ sv, float* __restrict__ out)
{
    __shared__ __align__(16) float rbuf[128][52];
    __shared__ __align__(16) float scal[128][8];
    __shared__ __align__(16) float qgL[NRBF][12];
    __shared__ __align__(16) float qnL[NRBF][12];
    __shared__ int   eSrc[128];
    __shared__ int   eZd[128];
    __shared__ float cv[40];

    const int tid = threadIdx.x;
    const int f = tid;

    // stage Qg/Qn (padded rows of 12 for aligned float4 reads) and constant vectors
    for (int i = tid; i < NRBF*12; i += 128) {
        int j = i / 12, c = i % 12;
        qgL[j][c] = (c < NGATE) ? Qg[j*NGATE + c] : 0.f;
        qnL[j][c] = (c < NGATE) ? Qn[j*NGATE + c] : 0.f;
    }
    if (tid < 40) cv[tid] = sv[512 + tid];

    // per-lane persistent: R columns (padded to 52 with zeros), s/d constants
    float R0c[52], R1c[52];
    #pragma unroll
    for (int j = 0; j < NRBF; j++) { R0c[j] = R0[j*FOUT + f]; R1c[j] = R1[j*FOUT + f]; }
    R0c[50] = R0c[51] = 0.f; R1c[50] = R1c[51] = 0.f;
    float s0v = sv[f], s1v = sv[128+f], d0v = sv[256+f], d1v = sv[384+f];
    __syncthreads();

    const int eBeg = blockIdx.x * EPB;
    const int eEnd = min(NEDGES, eBeg + EPB);

    float accA = 0.f, accX = 0.f, accY = 0.f, accZ = 0.f;
    float ti0 = 0.f, ti1 = 0.f;
    int cur = -1;

    for (int base = eBeg; base < eEnd; base += 128) {
        int nb = min(128, eEnd - base);
        __syncthreads();   // protect rbuf/scal from previous batch's readers

        // ---- Phase A: one lane per edge ----
        if (tid < nb) {
            int eid = sorted[base + tid];
            float w = ew[eid];
            int se = esrc[eid];
            int de = edst[eid];
            int zd = z[de];
            float ex = evec[eid*3+0], ey = evec[eid*3+1], ez = evec[eid*3+2];
            float rn = rsqrtf(ex*ex + ey*ey + ez*ez);
            ex *= rn; ey *= rn; ez *= rn;
            float C = (w < OUTERC) ? 0.5f*(cosf(w*PI_OVER_OUTER) + 1.0f) : 0.0f;

            float rr[52];
            #pragma unroll
            for (int j = 0; j < NRBF; j++) {
                float tt = w - RBF_D * (float)j;
                rr[j] = exp2f(RBF_C2 * tt * tt);
            }
            rr[50] = rr[51] = 0.f;
            #pragma unroll
            for (int q = 0; q < 13; q++) {
                *((float4*)&rbuf[tid][4*q]) = make_float4(rr[4*q], rr[4*q+1], rr[4*q+2], rr[4*q+3]);
            }

            // H = C*(r@Qg + gc1) + gc2 + noise * softplus(C*(r@Qn + nc1) + nc2)
            float hg[NGATE], hn[NGATE];
            #pragma unroll
            for (int t = 0; t < NGATE; t++) { hg[t] = 0.f; hn[t] = 0.f; }
            #pragma unroll
            for (int j = 0; j < NRBF; j++) {
                float rj = rr[j];
                #pragma unroll
                for (int t = 0; t < NGATE; t++) {
                    hg[t] = fmaf(rj, qgL[j][t], hg[t]);
                    hn[t] = fmaf(rj, qnL[j][t], hn[t]);
                }
            }
            float H[NGATE];
            #pragma unroll
            for (int t = 0; t < NGATE; t++) {
                float gv = C*(hg[t] + cv[t]) + cv[10+t];
                float nv = C*(hn[t] + cv[20+t]) + cv[30+t];
                H[t] = gv + noise[(long long)eid*NGATE + t] * softplusf(nv);
            }
            // top-2
            float m1 = -INFINITY, m2 = -INFINITY;
            #pragma unroll
            for (int t = 0; t < NGATE; t++) {
                float v = H[t];
                if (v > m1) { m2 = m1; m1 = v; } else if (v > m2) { m2 = v; }
            }
            // masked-softmax denominator (handles ties like the reference)
            float den = 0.f;
            #pragma unroll
            for (int t = 0; t < NGATE; t++) den += (H[t] >= m2) ? __expf(H[t] - m1) : 0.f;
            float inv = 1.0f / den;
            float g0 = inv;
            float g1 = __expf(m2 - m1) * inv;

            scal[tid][0] = C*g0; scal[tid][1] = C*g1; scal[tid][2] = g0; scal[tid][3] = g1;
            scal[tid][4] = ex;   scal[tid][5] = ey;   scal[tid][6] = ez; scal[tid][7] = 0.f;
            eSrc[tid] = se; eZd[tid] = zd;
        }
        __syncthreads();

        // ---- Phase B: one lane per output column f ----
        for (int i = 0; i < nb; i++) {
            int se = eSrc[i];
            if (se != cur) {
                if (cur >= 0) {
                    atomicAdd(&out[(long long)cur*FOUT + f], accA);
                    float* vb = out + (long long)NATOMS*FOUT + (long long)cur*3*FOUT;
                    atomicAdd(&vb[f], accX);
                    atomicAdd(&vb[FOUT + f], accY);
                    atomicAdd(&vb[2*FOUT + f], accZ);
                }
                cur = se;
                accA = accX = accY = accZ = 0.f;
                int zs = z[cur];
                ti0 = Ti0[zs*FOUT + f];
                ti1 = Ti1[zs*FOUT + f];
            }
            int zd = eZd[i];
            float tj0 = Tj0[zd*FOUT + f];
            float tj1 = Tj1[zd*FOUT + f];
            float4 sA = *((const float4*)&scal[i][0]);
            float4 sB = *((const float4*)&scal[i][4]);
            float a0 = sA.x, a1 = sA.y, g0 = sA.z, g1 = sA.w;

            float acc0 = 0.f, acc1 = 0.f;
            #pragma unroll
            for (int q = 0; q < 13; q++) {
                float4 r4 = *((const float4*)&rbuf[i][4*q]);
                acc0 += r4.x*R0c[4*q] + r4.y*R0c[4*q+1] + r4.z*R0c[4*q+2] + r4.w*R0c[4*q+3];
                acc1 += r4.x*R1c[4*q] + r4.y*R1c[4*q+1] + r4.z*R1c[4*q+2] + r4.w*R1c[4*q+3];
            }
            float eo = a0*(acc0 + s0v) + g0*(d0v + ti0 + tj0)
                     + a1*(acc1 + s1v) + g1*(d1v + ti1 + tj1);
            accA += eo;
            accX = fmaf(sB.x, eo, accX);
            accY = fmaf(sB.y, eo, accY);
            accZ = fmaf(sB.z, eo, accZ);
        }
    }
    if (cur >= 0) {
        atomicAdd(&out[(long long)cur*FOUT + f], accA);
        float* vb = out + (long long)NATOMS*FOUT + (long long)cur*3*FOUT;
        atomicAdd(&vb[f], accX);
        atomicAdd(&vb[FOUT + f], accY);
        atomicAdd(&vb[2*FOUT + f], accZ);
    }
}

extern "C" void kernel_launch(void* const* d_in, const int* in_sizes, int n_in,
                              void* d_out, int out_size, void* d_ws, size_t ws_size,
                              hipStream_t stream)
{
    const int*   z    = (const int*)d_in[0];
    // d_in[1] = pos (unused), d_in[2] = batch (unused)
    const int*   ei   = (const int*)d_in[3];
    const int*   esrc = ei;
    const int*   edst = ei + NEDGES;
    const float* ew   = (const float*)d_in[4];
    const float* evec = (const float*)d_in[5];
    const float* nz   = (const float*)d_in[6];
    const float* emb  = (const float*)d_in[7];
    const float* Wd   = (const float*)d_in[8];
    const float* bd   = (const float*)d_in[9];
    const float* Wdt  = (const float*)d_in[10];
    const float* bdt  = (const float*)d_in[11];
    const float* Wai  = (const float*)d_in[12];
    const float* bai  = (const float*)d_in[13];
    const float* Waj  = (const float*)d_in[14];
    const float* baj  = (const float*)d_in[15];
    const float* Wgam = (const float*)d_in[16];
    const float* bgam = (const float*)d_in[17];
    const float* Wg   = (const float*)d_in[18];
    const float* Wn   = (const float*)d_in[19];
    const float* Wexp = (const float*)d_in[20];
    const float* bexp = (const float*)d_in[21];
    float* out = (float*)d_out;

    // workspace carve-up (~2.8 MB total)
    char* w = (char*)d_ws;
    auto alloc = [&](size_t bytes) -> void* {
        void* p = (void*)w;
        w += (bytes + 255) & ~(size_t)255;
        return p;
    };
    int*   counts  = (int*)alloc(NATOMS * 4);
    int*   cursors = (int*)alloc(NATOMS * 4);
    int*   sorted  = (int*)alloc((size_t)NEDGES * 4);
    float* E1i = (float*)alloc(100*EMBD*4);
    float* E1j = (float*)alloc(100*EMBD*4);
    float* E2i = (float*)alloc(100*EMBD*4);
    float* E2j = (float*)alloc(100*EMBD*4);
    float* A1  = (float*)alloc(NRBF*EMBD*4);
    float* u1  = (float*)alloc(EMBD*4);
    float* M0  = (float*)alloc(EMBD*FOUT*4);
    float* M1  = (float*)alloc(EMBD*FOUT*4);
    float* R0  = (float*)alloc(NRBF*FOUT*4);
    float* R1  = (float*)alloc(NRBF*FOUT*4);
    float* Qg  = (float*)alloc(NRBF*NGATE*4);
    float* Qn  = (float*)alloc(NRBF*NGATE*4);
    float* Ti0 = (float*)alloc(100*FOUT*4);
    float* Ti1 = (float*)alloc(100*FOUT*4);
    float* Tj0 = (float*)alloc(100*FOUT*4);
    float* Tj1 = (float*)alloc(100*FOUT*4);
    float* sv  = (float*)alloc(552*4);

    hipMemsetAsync(counts, 0, NATOMS*4, stream);
    hipMemsetAsync(d_out, 0, (size_t)out_size*4, stream);

    // pre1: 129792 matmul threads + NEDGES counting threads
    {
        int grid = (129792 + NEDGES + 255) / 256;
        k_pre1<<<grid, 256, 0, stream>>>(emb, Wai, bai, Waj, baj, Wd, Wdt, bd, Wgam, Wexp,
                                         esrc, counts, E1i, E1j, A1, u1, M0, M1);
    }
    // pre2: 257 matmul blocks + 1 scan block
    k_pre2<<<P2_MM_BLOCKS + 1, 256, 0, stream>>>(Wgam, Wg, Wn, bdt, bgam, Wexp, bexp,
                                                 E1i, E1j, A1, u1, M0, M1,
                                                 E2i, E2j, R0, R1, Qg, Qn, sv,
                                                 counts, cursors);
    // pre3: 200 table blocks + scatter blocks
    {
        int grid = P3_MM_BLOCKS + (NEDGES + 255) / 256;
        k_pre3<<<grid, 256, 0, stream>>>(E2i, E2j, Wexp, Ti0, Ti1, Tj0, Tj1,
                                         esrc, cursors, sorted);
    }
    // main
    {
        int grid = (NEDGES + EPB - 1) / EPB;
        k_main<<<grid, 128, 0, stream>>>(z, esrc, edst, ew, evec, nz, sorted,
                                         R0, R1, Qg, Qn, Ti0, Ti1, Tj0, Tj1, sv, out);
    }
}

// Round 2
// 504.894 us; speedup vs baseline: 4.1197x; 4.1197x over previous
//
#include <hip/hip_runtime.h>
#include <math.h>

#define NATOMS 20000
#define NEDGES 400000
#define EMBD   256
#define NRBF   50
#define NGATE  10
#define FOUT   128
#define APB    8       // atoms per block in k_main
#define OUTERC 5.0f

// RBF constants: offset_j = j*(5/49), coeff = -0.5/(5/49)^2, folded log2(e) for exp2
#define RBF_D   (5.0f/49.0f)
#define RBF_INVD (49.0f/5.0f)
#define RBF_C2  (-0.5f*(49.0f/5.0f)*(49.0f/5.0f)*1.4426950408889634f)
#define PI_OVER_OUTER 0.62831853071795864769f

static __device__ __forceinline__ float softplusf(float x){
    return (x > 15.0f) ? x : log1pf(__expf(x));
}
// round-to-nearest-even bf16, result in HIGH 16 bits of return
static __device__ __forceinline__ unsigned bfr(float v){
    unsigned u = __float_as_uint(v);
    return (u + 0x7fffu + ((u >> 16) & 1u)) & 0xffff0000u;
}

// ---------------- precompute 1: E1i,E1j,A1,u1,M0,M1 + edge counting ----------------
__global__ __launch_bounds__(256) void k_pre1(
    const float* __restrict__ emb, const float* __restrict__ Wai, const float* __restrict__ bai,
    const float* __restrict__ Waj, const float* __restrict__ baj, const float* __restrict__ Wd,
    const float* __restrict__ Wdt, const float* __restrict__ bd, const float* __restrict__ Wgam,
    const float* __restrict__ Wexp, const int* __restrict__ esrc,
    int* __restrict__ counts,
    float* __restrict__ E1i, float* __restrict__ E1j, float* __restrict__ A1,
    float* __restrict__ u1, float* __restrict__ M0, float* __restrict__ M1)
{
    long long gid = (long long)blockIdx.x * 256 + threadIdx.x;
    if (gid < 25600) {
        int m = (int)gid / 256, n = (int)gid % 256;
        float s = bai[n];
        for (int k = 0; k < EMBD; k++) s += emb[m*EMBD+k] * Wai[k*EMBD+n];
        E1i[gid] = s;
    } else if (gid < 51200) {
        int g = (int)gid - 25600; int m = g/256, n = g%256;
        float s = baj[n];
        for (int k = 0; k < EMBD; k++) s += emb[m*EMBD+k] * Waj[k*EMBD+n];
        E1j[g] = s;
    } else if (gid < 64000) {
        int g = (int)gid - 51200; int m = g/256, n = g%256;
        float s = 0.f;
        for (int k = 0; k < EMBD; k++) s += Wd[m*EMBD+k] * Wdt[k*EMBD+n];
        A1[g] = s;
    } else if (gid < 64256) {
        int n = (int)gid - 64000;
        float s = 0.f;
        for (int k = 0; k < EMBD; k++) s += bd[k] * Wdt[k*EMBD+n];
        u1[n] = s;
    } else if (gid < 97024) {
        int g = (int)gid - 64256; int m = g/128, n = g%128;
        float s = 0.f;
        for (int k = 0; k < EMBD; k++) s += Wgam[m*EMBD+k] * Wexp[k*FOUT+n];
        M0[g] = s;
    } else if (gid < 129792) {
        int g = (int)gid - 97024; int m = g/128, n = g%128;
        const float* W1 = Wexp + EMBD*FOUT;
        float s = 0.f;
        for (int k = 0; k < EMBD; k++) s += Wgam[m*EMBD+k] * W1[k*FOUT+n];
        M1[g] = s;
    } else {
        long long e = gid - 129792;
        if (e < NEDGES) atomicAdd(&counts[esrc[e]], 1);
    }
}

// ---------------- precompute 2: E2i,E2j,R0,R1,Qg,Qn,sv + prefix scan ----------------
// Qg/Qn stored padded [52][12]; rows 50,51 zeroed (window overrun guard).
// sv: [0..127]=s0, [128..255]=s1, [256..383]=d0, [384..511]=d1,
//     [512..521]=gc1, [522..531]=gc2, [532..541]=nc1, [542..551]=nc2
#define P2_MM_THREADS 65592
#define P2_MM_BLOCKS  257
__global__ __launch_bounds__(256) void k_pre2(
    const float* __restrict__ Wgam, const float* __restrict__ Wg, const float* __restrict__ Wn,
    const float* __restrict__ bdt, const float* __restrict__ bgam,
    const float* __restrict__ Wexp, const float* __restrict__ bexp,
    const float* __restrict__ E1i, const float* __restrict__ E1j,
    const float* __restrict__ A1, const float* __restrict__ u1,
    const float* __restrict__ M0, const float* __restrict__ M1,
    float* __restrict__ E2i, float* __restrict__ E2j,
    float* __restrict__ R0, float* __restrict__ R1,
    float* __restrict__ Qg, float* __restrict__ Qn, float* __restrict__ sv,
    const int* __restrict__ counts, int* __restrict__ cursors)
{
    if (blockIdx.x == P2_MM_BLOCKS) {
        __shared__ int part[256];
        int t = threadIdx.x;
        const int CH = (NATOMS + 255) / 256;
        int base = t * CH;
        int s = 0;
        for (int i = 0; i < CH; i++) { int idx = base + i; if (idx < NATOMS) s += counts[idx]; }
        part[t] = s;
        __syncthreads();
        for (int d = 1; d < 256; d <<= 1) {
            int v = (t >= d) ? part[t - d] : 0;
            __syncthreads();
            part[t] += v;
            __syncthreads();
        }
        int run = (t == 0) ? 0 : part[t - 1];
        for (int i = 0; i < CH; i++) {
            int idx = base + i;
            if (idx < NATOMS) { cursors[idx] = run; run += counts[idx]; }
        }
        return;
    }
    long long gid = (long long)blockIdx.x * 256 + threadIdx.x;
    if (gid >= P2_MM_THREADS) return;
    if (gid < 25600) {
        int m = (int)gid / 256, n = (int)gid % 256;
        const float* Wg1 = Wgam + 256*EMBD;
        float s = 0.f;
        for (int k = 0; k < EMBD; k++) s += E1i[m*EMBD+k] * Wg1[k*EMBD+n];
        E2i[gid] = s;
    } else if (gid < 51200) {
        int g = (int)gid - 25600; int m = g/256, n = g%256;
        const float* Wg2 = Wgam + 512*EMBD;
        float s = 0.f;
        for (int k = 0; k < EMBD; k++) s += E1j[m*EMBD+k] * Wg2[k*EMBD+n];
        E2j[g] = s;
    } else if (gid < 57600) {
        int g = (int)gid - 51200; int m = g/128, n = g%128;
        float s = 0.f;
        for (int k = 0; k < EMBD; k++) s += A1[m*EMBD+k] * M0[k*FOUT+n];
        R0[g] = s;
    } else if (gid < 64000) {
        int g = (int)gid - 57600; int m = g/128, n = g%128;
        float s = 0.f;
        for (int k = 0; k < EMBD; k++) s += A1[m*EMBD+k] * M1[k*FOUT+n];
        R1[g] = s;
    } else if (gid < 64520) {
        int g = (int)gid - 64000; int m = g/10, t = g%10;   // m in [0,52)
        float s = 0.f;
        if (m < 50) for (int k = 0; k < EMBD; k++) s += A1[m*EMBD+k] * Wg[k*NGATE+t];
        Qg[m*12+t] = s;
    } else if (gid < 65040) {
        int g = (int)gid - 64520; int m = g/10, t = g%10;
        float s = 0.f;
        if (m < 50) for (int k = 0; k < EMBD; k++) s += A1[m*EMBD+k] * Wn[k*NGATE+t];
        Qn[m*12+t] = s;
    } else {
        int i = (int)gid - 65040;  // < 552
        if (i < 128) {
            float s = 0.f;
            for (int k = 0; k < EMBD; k++) s += u1[k] * M0[k*FOUT+i];
            sv[i] = s;
        } else if (i < 256) {
            int f = i - 128; float s = 0.f;
            for (int k = 0; k < EMBD; k++) s += u1[k] * M1[k*FOUT+f];
            sv[i] = s;
        } else if (i < 384) {
            int f = i - 256; float s = bexp[f];
            for (int k = 0; k < EMBD; k++) s += bdt[k]*M0[k*FOUT+f] + bgam[k]*Wexp[k*FOUT+f];
            sv[i] = s;
        } else if (i < 512) {
            int f = i - 384; float s = bexp[FOUT+f];
            const float* W1 = Wexp + EMBD*FOUT;
            for (int k = 0; k < EMBD; k++) s += bdt[k]*M1[k*FOUT+f] + bgam[k]*W1[k*FOUT+f];
            sv[i] = s;
        } else if (i < 522) {
            int t = i - 512; float s = 0.f;
            for (int k = 0; k < EMBD; k++) s += u1[k] * Wg[k*NGATE+t];
            sv[i] = s;
        } else if (i < 532) {
            int t = i - 522; float s = 0.f;
            for (int k = 0; k < EMBD; k++) s += bdt[k] * Wg[k*NGATE+t];
            sv[i] = s;
        } else if (i < 542) {
            int t = i - 532; float s = 0.f;
            for (int k = 0; k < EMBD; k++) s += u1[k] * Wn[k*NGATE+t];
            sv[i] = s;
        } else {
            int t = i - 542; float s = 0.f;
            for (int k = 0; k < EMBD; k++) s += bdt[k] * Wn[k*NGATE+t];
            sv[i] = s;
        }
    }
}

// ---------------- precompute 3: Ti/Tj tables + edge transform & scatter ----------------
// Edge branch: reads everything COALESCED in original edge order, computes
// gates/cutoff/normalized dirs, scatter-writes compact SoA records to CSR slot.
#define P3_MM_BLOCKS 200
__global__ __launch_bounds__(256) void k_pre3(
    const float* __restrict__ E2i, const float* __restrict__ E2j,
    const float* __restrict__ Wexp,
    float* __restrict__ Ti0, float* __restrict__ Ti1,
    float* __restrict__ Tj0, float* __restrict__ Tj1,
    const int* __restrict__ z, const int* __restrict__ esrc, const int* __restrict__ edst,
    const float* __restrict__ ew, const float* __restrict__ evec, const float* __restrict__ noise,
    const float* __restrict__ Qg, const float* __restrict__ Qn, const float* __restrict__ sv,
    int* __restrict__ cursors,
    float* __restrict__ wS, unsigned* __restrict__ abS, unsigned* __restrict__ ggS,
    unsigned* __restrict__ xyS, unsigned* __restrict__ ezdS)
{
    if (blockIdx.x >= P3_MM_BLOCKS) {
        long long e = (long long)(blockIdx.x - P3_MM_BLOCKS) * 256 + threadIdx.x;
        if (e >= NEDGES) return;
        float w = ew[e];
        float C = (w < OUTERC) ? 0.5f*(cosf(w*PI_OVER_OUTER) + 1.0f) : 0.0f;
        int j0 = ((int)(w * RBF_INVD) - 6) & ~3;
        j0 = max(0, min(36, j0));
        float rW[16];
        #pragma unroll
        for (int k = 0; k < 16; k++) { float t = w - (j0+k)*RBF_D; rW[k] = exp2f(RBF_C2*t*t); }
        float hg[NGATE], hn[NGATE];
        #pragma unroll
        for (int t = 0; t < NGATE; t++) { hg[t] = 0.f; hn[t] = 0.f; }
        #pragma unroll
        for (int k = 0; k < 16; k++) {
            float rk = rW[k];
            const float* qg = &Qg[(j0+k)*12];
            const float* qn = &Qn[(j0+k)*12];
            float4 ga = *(const float4*)qg; float4 gb = *(const float4*)(qg+4);
            float2 gc = *(const float2*)(qg+8);
            float4 na = *(const float4*)qn; float4 nb = *(const float4*)(qn+4);
            float2 nc = *(const float2*)(qn+8);
            hg[0]=fmaf(rk,ga.x,hg[0]); hg[1]=fmaf(rk,ga.y,hg[1]); hg[2]=fmaf(rk,ga.z,hg[2]); hg[3]=fmaf(rk,ga.w,hg[3]);
            hg[4]=fmaf(rk,gb.x,hg[4]); hg[5]=fmaf(rk,gb.y,hg[5]); hg[6]=fmaf(rk,gb.z,hg[6]); hg[7]=fmaf(rk,gb.w,hg[7]);
            hg[8]=fmaf(rk,gc.x,hg[8]); hg[9]=fmaf(rk,gc.y,hg[9]);
            hn[0]=fmaf(rk,na.x,hn[0]); hn[1]=fmaf(rk,na.y,hn[1]); hn[2]=fmaf(rk,na.z,hn[2]); hn[3]=fmaf(rk,na.w,hn[3]);
            hn[4]=fmaf(rk,nb.x,hn[4]); hn[5]=fmaf(rk,nb.y,hn[5]); hn[6]=fmaf(rk,nb.z,hn[6]); hn[7]=fmaf(rk,nb.w,hn[7]);
            hn[8]=fmaf(rk,nc.x,hn[8]); hn[9]=fmaf(rk,nc.y,hn[9]);
        }
        float H[NGATE];
        #pragma unroll
        for (int t = 0; t < NGATE; t++) {
            float gv = C*(hg[t] + sv[512+t]) + sv[522+t];
            float nv = C*(hn[t] + sv[532+t]) + sv[542+t];
            H[t] = gv + noise[(long long)e*NGATE + t] * softplusf(nv);
        }
        float m1 = -INFINITY, m2 = -INFINITY;
        #pragma unroll
        for (int t = 0; t < NGATE; t++) {
            float v = H[t];
            if (v > m1) { m2 = m1; m1 = v; } else if (v > m2) { m2 = v; }
        }
        float den = 0.f;
        #pragma unroll
        for (int t = 0; t < NGATE; t++) den += (H[t] >= m2) ? __expf(H[t] - m1) : 0.f;
        float inv = 1.0f / den;
        float g0 = inv;
        float g1 = __expf(m2 - m1) * inv;

        float ex = evec[e*3+0], ey = evec[e*3+1], ez = evec[e*3+2];
        float rn = rsqrtf(ex*ex + ey*ey + ez*ez);
        ex *= rn; ey *= rn; ez *= rn;
        int zd = z[edst[e]];
        int p = atomicAdd(&cursors[esrc[e]], 1);
        wS[p]  = w;
        abS[p] = (bfr(C*g0) >> 16) | bfr(C*g1);
        ggS[p] = (bfr(g0) >> 16)   | bfr(g1);
        xyS[p] = (bfr(ex) >> 16)   | bfr(ey);
        ezdS[p]= bfr(ez) | ((unsigned)j0 << 8) | (unsigned)zd;
        return;
    }
    int gid = blockIdx.x * 256 + threadIdx.x;   // < 51200
    const float* W1 = Wexp + EMBD*FOUT;
    if (gid < 12800) {
        int m = gid/128, ff = gid%128; float s = 0.f;
        for (int k = 0; k < EMBD; k++) s += E2i[m*EMBD+k] * Wexp[k*FOUT+ff];
        Ti0[gid] = s;
    } else if (gid < 25600) {
        int g = gid-12800; int m = g/128, ff = g%128; float s = 0.f;
        for (int k = 0; k < EMBD; k++) s += E2i[m*EMBD+k] * W1[k*FOUT+ff];
        Ti1[g] = s;
    } else if (gid < 38400) {
        int g = gid-25600; int m = g/128, ff = g%128; float s = 0.f;
        for (int k = 0; k < EMBD; k++) s += E2j[m*EMBD+k] * Wexp[k*FOUT+ff];
        Tj0[g] = s;
    } else {
        int g = gid-38400; int m = g/128, ff = g%128; float s = 0.f;
        for (int k = 0; k < EMBD; k++) s += E2j[m*EMBD+k] * W1[k*FOUT+ff];
        Tj1[g] = s;
    }
}

// ---------------- main kernel: 8 atoms per block (CSR-owned), 128 threads ----------------
#define LDSROW 24
#define DSTEP(V,KK) acc0=fmaf(V,R0c[KK],acc0); acc1=fmaf(V,R1c[KK],acc1);
#define DOT(J) { acc0=c0.x*R0c[J]; acc1=c0.x*R1c[J]; \
  DSTEP(c0.y,(J)+1) DSTEP(c0.z,(J)+2) DSTEP(c0.w,(J)+3) \
  DSTEP(c1.x,(J)+4) DSTEP(c1.y,(J)+5) DSTEP(c1.z,(J)+6) DSTEP(c1.w,(J)+7) \
  DSTEP(c2.x,(J)+8) DSTEP(c2.y,(J)+9) DSTEP(c2.z,(J)+10) DSTEP(c2.w,(J)+11) \
  DSTEP(c3.x,(J)+12) DSTEP(c3.y,(J)+13) DSTEP(c3.z,(J)+14) DSTEP(c3.w,(J)+15) }

__global__ __launch_bounds__(128) void k_main(
    const int* __restrict__ z, const int* __restrict__ cursors,
    const float* __restrict__ wS, const unsigned* __restrict__ abS,
    const unsigned* __restrict__ ggS, const unsigned* __restrict__ xyS,
    const unsigned* __restrict__ ezdS,
    const float* __restrict__ R0, const float* __restrict__ R1,
    const float* __restrict__ Ti0, const float* __restrict__ Ti1,
    const float* __restrict__ Tj0, const float* __restrict__ Tj1,
    const float* __restrict__ sv, float* __restrict__ out)
{
    __shared__ float lds[128*LDSROW];
    const int f = threadIdx.x;

    float R0c[52], R1c[52];
    #pragma unroll
    for (int j = 0; j < NRBF; j++) { R0c[j] = R0[j*FOUT + f]; R1c[j] = R1[j*FOUT + f]; }
    R0c[50]=R0c[51]=0.f; R1c[50]=R1c[51]=0.f;
    float s0v = sv[f], s1v = sv[128+f], d0v = sv[256+f], d1v = sv[384+f];

    const int aBeg = blockIdx.x * APB;
    const int aEnd = min(NATOMS, aBeg + APB);
    const int eBeg = (aBeg == 0) ? 0 : cursors[aBeg-1];
    const int eEnd = cursors[aEnd-1];

    int aCur = aBeg;
    int nextEnd = cursors[aCur];
    float ti0 = Ti0[z[aCur]*FOUT + f];
    float ti1 = Ti1[z[aCur]*FOUT + f];
    float accA=0.f, accX=0.f, accY=0.f, accZ=0.f;

    for (int base = eBeg; base < eEnd; base += 128) {
        int nb = min(128, eEnd - base);
        __syncthreads();
        if (f < nb) {
            int p = base + f;
            float w = wS[p];
            unsigned ab = abS[p], gg = ggS[p], xy = xyS[p], ezd = ezdS[p];
            int j0 = (ezd >> 8) & 0x3f;
            int zd = ezd & 0xff;
            float rr[16];
            #pragma unroll
            for (int k = 0; k < 16; k++) { float t = w - (j0+k)*RBF_D; rr[k] = exp2f(RBF_C2*t*t); }
            float* row = &lds[f*LDSROW];
            #pragma unroll
            for (int q = 0; q < 4; q++)
                *(float4*)&row[4*q] = make_float4(rr[4*q], rr[4*q+1], rr[4*q+2], rr[4*q+3]);
            *(float4*)&row[16] = make_float4(
                __uint_as_float(ab << 16), __uint_as_float(ab & 0xffff0000u),
                __uint_as_float(gg << 16), __uint_as_float(gg & 0xffff0000u));
            *(float4*)&row[20] = make_float4(
                __uint_as_float(xy << 16), __uint_as_float(xy & 0xffff0000u),
                __uint_as_float(ezd & 0xffff0000u), __int_as_float((j0 << 16) | zd));
        }
        __syncthreads();

        // pipelined phase B
        float4 c0,c1,c2,c3,cs0,cs1;
        {
            const float* row = &lds[0];
            c0=*(const float4*)&row[0]; c1=*(const float4*)&row[4];
            c2=*(const float4*)&row[8]; c3=*(const float4*)&row[12];
            cs0=*(const float4*)&row[16]; cs1=*(const float4*)&row[20];
        }
        int auxc = __builtin_amdgcn_readfirstlane(__float_as_int(cs1.w));
        int zdc = auxc & 0xffff, j0c = auxc >> 16;
        float tj0c = Tj0[zdc*FOUT + f], tj1c = Tj1[zdc*FOUT + f];

        for (int i = 0; i < nb; i++) {
            float4 p0,p1,p2,p3,ps0,ps1;
            if (i + 1 < nb) {
                const float* row = &lds[(i+1)*LDSROW];
                p0=*(const float4*)&row[0]; p1=*(const float4*)&row[4];
                p2=*(const float4*)&row[8]; p3=*(const float4*)&row[12];
                ps0=*(const float4*)&row[16]; ps1=*(const float4*)&row[20];
            }
            int gi = base + i;
            while (gi == nextEnd) {   // flush finished atoms (incl. empty ones)
                out[(size_t)aCur*FOUT + f] = accA;
                float* vb = out + (size_t)NATOMS*FOUT + (size_t)aCur*3*FOUT;
                vb[f] = accX; vb[FOUT+f] = accY; vb[2*FOUT+f] = accZ;
                accA = accX = accY = accZ = 0.f;
                aCur++;
                nextEnd = cursors[aCur];
                int zs = z[aCur];
                ti0 = Ti0[zs*FOUT + f]; ti1 = Ti1[zs*FOUT + f];
            }
            float acc0, acc1;
            switch (j0c >> 2) {
                case 0: DOT(0)  break;
                case 1: DOT(4)  break;
                case 2: DOT(8)  break;
                case 3: DOT(12) break;
                case 4: DOT(16) break;
                case 5: DOT(20) break;
                case 6: DOT(24) break;
                case 7: DOT(28) break;
                case 8: DOT(32) break;
                default: DOT(36) break;
            }
            float eo = cs0.x*(acc0 + s0v) + cs0.z*(d0v + ti0 + tj0c)
                     + cs0.y*(acc1 + s1v) + cs0.w*(d1v + ti1 + tj1c);
            accA += eo;
            accX = fmaf(cs1.x, eo, accX);
            accY = fmaf(cs1.y, eo, accY);
            accZ = fmaf(cs1.z, eo, accZ);
            if (i + 1 < nb) {
                c0=p0; c1=p1; c2=p2; c3=p3; cs0=ps0; cs1=ps1;
                auxc = __builtin_amdgcn_readfirstlane(__float_as_int(ps1.w));
                zdc = auxc & 0xffff; j0c = auxc >> 16;
                tj0c = Tj0[zdc*FOUT + f]; tj1c = Tj1[zdc*FOUT + f];
            }
        }
    }
    // flush remaining owned atoms (last one with data + trailing empties)
    while (aCur < aEnd) {
        out[(size_t)aCur*FOUT + f] = accA;
        float* vb = out + (size_t)NATOMS*FOUT + (size_t)aCur*3*FOUT;
        vb[f] = accX; vb[FOUT+f] = accY; vb[2*FOUT+f] = accZ;
        accA = accX = accY = accZ = 0.f;
        aCur++;
    }
}

extern "C" void kernel_launch(void* const* d_in, const int* in_sizes, int n_in,
                              void* d_out, int out_size, void* d_ws, size_t ws_size,
                              hipStream_t stream)
{
    const int*   z    = (const int*)d_in[0];
    const int*   ei   = (const int*)d_in[3];
    const int*   esrc = ei;
    const int*   edst = ei + NEDGES;
    const float* ew   = (const float*)d_in[4];
    const float* evec = (const float*)d_in[5];
    const float* nz   = (const float*)d_in[6];
    const float* emb  = (const float*)d_in[7];
    const float* Wd   = (const float*)d_in[8];
    const float* bd   = (const float*)d_in[9];
    const float* Wdt  = (const float*)d_in[10];
    const float* bdt  = (const float*)d_in[11];
    const float* Wai  = (const float*)d_in[12];
    const float* bai  = (const float*)d_in[13];
    const float* Waj  = (const float*)d_in[14];
    const float* baj  = (const float*)d_in[15];
    const float* Wgam = (const float*)d_in[16];
    const float* bgam = (const float*)d_in[17];
    const float* Wg   = (const float*)d_in[18];
    const float* Wn   = (const float*)d_in[19];
    const float* Wexp = (const float*)d_in[20];
    const float* bexp = (const float*)d_in[21];
    float* out = (float*)d_out;

    char* w = (char*)d_ws;
    auto alloc = [&](size_t bytes) -> void* {
        void* p = (void*)w;
        w += (bytes + 255) & ~(size_t)255;
        return p;
    };
    int*   counts  = (int*)alloc(NATOMS * 4);
    int*   cursors = (int*)alloc(NATOMS * 4);
    float* E1i = (float*)alloc(100*EMBD*4);
    float* E1j = (float*)alloc(100*EMBD*4);
    float* E2i = (float*)alloc(100*EMBD*4);
    float* E2j = (float*)alloc(100*EMBD*4);
    float* A1  = (float*)alloc(NRBF*EMBD*4);
    float* u1  = (float*)alloc(EMBD*4);
    float* M0  = (float*)alloc(EMBD*FOUT*4);
    float* M1  = (float*)alloc(EMBD*FOUT*4);
    float* R0  = (float*)alloc(NRBF*FOUT*4);
    float* R1  = (float*)alloc(NRBF*FOUT*4);
    float* Qg  = (float*)alloc(52*12*4);
    float* Qn  = (float*)alloc(52*12*4);
    float* Ti0 = (float*)alloc(100*FOUT*4);
    float* Ti1 = (float*)alloc(100*FOUT*4);
    float* Tj0 = (float*)alloc(100*FOUT*4);
    float* Tj1 = (float*)alloc(100*FOUT*4);
    float* sv  = (float*)alloc(552*4);
    float*    wS   = (float*)alloc((size_t)NEDGES*4);
    unsigned* abS  = (unsigned*)alloc((size_t)NEDGES*4);
    unsigned* ggS  = (unsigned*)alloc((size_t)NEDGES*4);
    unsigned* xyS  = (unsigned*)alloc((size_t)NEDGES*4);
    unsigned* ezdS = (unsigned*)alloc((size_t)NEDGES*4);

    hipMemsetAsync(counts, 0, NATOMS*4, stream);

    {
        int grid = (129792 + NEDGES + 255) / 256;
        k_pre1<<<grid, 256, 0, stream>>>(emb, Wai, bai, Waj, baj, Wd, Wdt, bd, Wgam, Wexp,
                                         esrc, counts, E1i, E1j, A1, u1, M0, M1);
    }
    k_pre2<<<P2_MM_BLOCKS + 1, 256, 0, stream>>>(Wgam, Wg, Wn, bdt, bgam, Wexp, bexp,
                                                 E1i, E1j, A1, u1, M0, M1,
                                                 E2i, E2j, R0, R1, Qg, Qn, sv,
                                                 counts, cursors);
    {
        int grid = P3_MM_BLOCKS + (NEDGES + 255) / 256;
        k_pre3<<<grid, 256, 0, stream>>>(E2i, E2j, Wexp, Ti0, Ti1, Tj0, Tj1,
                                         z, esrc, edst, ew, evec, nz,
                                         Qg, Qn, sv, cursors,
                                         wS, abS, ggS, xyS, ezdS);
    }
    {
        int grid = NATOMS / APB;   // 2500
        k_main<<<grid, 128, 0, stream>>>(z, cursors, wS, abS, ggS, xyS, ezdS,
                                         R0, R1, Ti0, Ti1, Tj0, Tj1, sv, out);
    }
}

// Round 3
// 447.502 us; speedup vs baseline: 4.6481x; 1.1283x over previous
//
#include <hip/hip_runtime.h>
#include <math.h>

#define NATOMS 20000
#define NEDGES 400000
#define EMBD   256
#define NRBF   50
#define NGATE  10
#define FOUT   128
#define APB    8       // atoms per block in k_main
#define OUTERC 5.0f

#define RBF_D    (5.0f/49.0f)
#define RBF_INVD (49.0f/5.0f)
#define RBF_C2   (-0.5f*(49.0f/5.0f)*(49.0f/5.0f)*1.4426950408889634f)
#define PI_OVER_OUTER 0.62831853071795864769f

static __device__ __forceinline__ float softplusf(float x){
    return (x > 15.0f) ? x : log1pf(__expf(x));
}
// round-to-nearest-even bf16, result in HIGH 16 bits
static __device__ __forceinline__ unsigned bfr(float v){
    unsigned u = __float_as_uint(v);
    return (u + 0x7fffu + ((u >> 16) & 1u)) & 0xffff0000u;
}

// ================= fused table/precompute kernel =================
// blocks 0..99   : i-side chain per atom type m:  E1i=emb[m]@Wai+bai -> E2i=E1i@Wgam1 -> Ti0/Ti1 rows
// blocks 100..199: j-side chain                  -> Tj0/Tj1 rows
// blocks 200..251: gate/R rows m=0..51 of Y=[A1(50); u1; bdt]:
//                  Y -> Z=Y@Wgam0 (+bgam for m=51) -> R0/R1 rows, s/d consts; gates Q=Y@{Wg,Wn}
// blocks 252..   : edge degree counting (atomicAdd)
__global__ __launch_bounds__(256) void k_tab(
    const float* __restrict__ emb,
    const float* __restrict__ Wai, const float* __restrict__ bai,
    const float* __restrict__ Waj, const float* __restrict__ baj,
    const float* __restrict__ Wgam,
    const float* __restrict__ Wexp, const float* __restrict__ bexp,
    const float* __restrict__ Wd, const float* __restrict__ Wdt,
    const float* __restrict__ bd, const float* __restrict__ bdt,
    const float* __restrict__ bgam,
    const float* __restrict__ Wg, const float* __restrict__ Wn,
    const int* __restrict__ esrc, int* __restrict__ counts,
    float* __restrict__ Ti0, float* __restrict__ Ti1,
    float* __restrict__ Tj0, float* __restrict__ Tj1,
    float* __restrict__ R0, float* __restrict__ R1,
    float* __restrict__ Qg, float* __restrict__ Qn, float* __restrict__ sv)
{
    const int b = blockIdx.x;
    const int t = threadIdx.x;
    if (b >= 252) {
        int e = (b - 252) * 256 + t;
        if (e < NEDGES) atomicAdd(&counts[esrc[e]], 1);
        return;
    }
    __shared__ float ya[256], za[256];
    if (b < 200) {
        const int side = (b >= 100);
        const int m = side ? b - 100 : b;
        const float* er = emb + m*EMBD;
        const float* W1 = side ? Waj : Wai;
        const float* b1 = side ? baj : bai;
        float s = b1[t];
        #pragma unroll 8
        for (int k = 0; k < EMBD; k++) s += er[k] * W1[k*EMBD + t];
        ya[t] = s;
        __syncthreads();
        const float* G = Wgam + (size_t)(side ? 512 : 256) * EMBD;
        s = 0.f;
        #pragma unroll 8
        for (int k = 0; k < EMBD; k++) s += ya[k] * G[k*EMBD + t];
        za[t] = s;
        __syncthreads();
        const int half = t >> 7, ff = t & 127;
        const float* WX = Wexp + (size_t)half*EMBD*FOUT;
        s = 0.f;
        #pragma unroll 8
        for (int k = 0; k < EMBD; k++) s += za[k] * WX[k*FOUT + ff];
        float* dst = side ? (half ? Tj1 : Tj0) : (half ? Ti1 : Ti0);
        dst[m*FOUT + ff] = s;
        return;
    }
    // gate/R rows
    const int m = b - 200;     // 0..51
    float s;
    if (m < 50) {
        const float* wr = Wd + m*EMBD;
        s = 0.f;
        #pragma unroll 8
        for (int k = 0; k < EMBD; k++) s += wr[k] * Wdt[k*EMBD + t];
    } else if (m == 50) {
        s = 0.f;
        #pragma unroll 8
        for (int k = 0; k < EMBD; k++) s += bd[k] * Wdt[k*EMBD + t];
    } else {
        s = bdt[t];
    }
    ya[t] = s;
    __syncthreads();
    s = 0.f;
    #pragma unroll 8
    for (int k = 0; k < EMBD; k++) s += ya[k] * Wgam[k*EMBD + t];
    if (m == 51) s += bgam[t];
    za[t] = s;
    __syncthreads();
    const int half = t >> 7, ff = t & 127;
    const float* WX = Wexp + (size_t)half*EMBD*FOUT;
    s = 0.f;
    #pragma unroll 8
    for (int k = 0; k < EMBD; k++) s += za[k] * WX[k*FOUT + ff];
    if (m < 50)       (half ? R1 : R0)[m*FOUT + ff] = s;
    else if (m == 50) sv[half*FOUT + ff] = s;
    else              sv[256 + half*FOUT + ff] = s + bexp[half*FOUT + ff];
    if (t < 20) {
        const int tt = t % 10;
        const float* WT = (t < 10) ? Wg : Wn;
        float q = 0.f;
        #pragma unroll 8
        for (int k = 0; k < EMBD; k++) q += ya[k] * WT[k*NGATE + tt];
        if (m < 50) { float* Q = (t < 10) ? Qg : Qn; Q[m*12 + tt] = q; }
        else {
            int off = (m == 50) ? ((t < 10) ? 512 : 532) : ((t < 10) ? 522 : 542);
            sv[off + tt] = q;
            float* Q = (t < 10) ? Qg : Qn; Q[m*12 + tt] = 0.f;   // zero-pad rows 50,51
        }
    }
}

// ================= exclusive scan of counts -> cursors =================
__global__ __launch_bounds__(256) void k_scan(const int* __restrict__ counts,
                                              int* __restrict__ cursors)
{
    __shared__ int part[256];
    int t = threadIdx.x;
    const int CH = (NATOMS + 255) / 256;
    int base = t * CH;
    int s = 0;
    for (int i = 0; i < CH; i++) { int idx = base + i; if (idx < NATOMS) s += counts[idx]; }
    part[t] = s;
    __syncthreads();
    for (int d = 1; d < 256; d <<= 1) {
        int v = (t >= d) ? part[t - d] : 0;
        __syncthreads();
        part[t] += v;
        __syncthreads();
    }
    int run = (t == 0) ? 0 : part[t - 1];
    for (int i = 0; i < CH; i++) {
        int idx = base + i;
        if (idx < NATOMS) { cursors[idx] = run; run += counts[idx]; }
    }
}

// ================= edge transform + CSR scatter =================
__global__ __launch_bounds__(256) void k_edge(
    const int* __restrict__ z, const int* __restrict__ esrc, const int* __restrict__ edst,
    const float* __restrict__ ew, const float* __restrict__ evec, const float* __restrict__ noise,
    const float* __restrict__ Qg, const float* __restrict__ Qn, const float* __restrict__ sv,
    int* __restrict__ cursors,
    float* __restrict__ wS, unsigned* __restrict__ abS, unsigned* __restrict__ ggS,
    unsigned* __restrict__ xyS, unsigned* __restrict__ ezdS)
{
    long long e = (long long)blockIdx.x * 256 + threadIdx.x;
    if (e >= NEDGES) return;
    float w = ew[e];
    float C = (w < OUTERC) ? 0.5f*(cosf(w*PI_OVER_OUTER) + 1.0f) : 0.0f;
    int iw = (int)(w * RBF_INVD);
    int j0 = (iw - 4) & ~3;
    j0 = max(0, min(40, j0));
    float rW[12];
    #pragma unroll
    for (int k = 0; k < 12; k++) { float t = w - (j0+k)*RBF_D; rW[k] = exp2f(RBF_C2*t*t); }
    float hg[NGATE], hn[NGATE];
    #pragma unroll
    for (int t = 0; t < NGATE; t++) { hg[t] = 0.f; hn[t] = 0.f; }
    #pragma unroll
    for (int k = 0; k < 12; k++) {
        float rk = rW[k];
        const float* qg = &Qg[(j0+k)*12];
        const float* qn = &Qn[(j0+k)*12];
        float4 ga = *(const float4*)qg; float4 gb = *(const float4*)(qg+4);
        float2 gc = *(const float2*)(qg+8);
        float4 na = *(const float4*)qn; float4 nb = *(const float4*)(qn+4);
        float2 nc = *(const float2*)(qn+8);
        hg[0]=fmaf(rk,ga.x,hg[0]); hg[1]=fmaf(rk,ga.y,hg[1]); hg[2]=fmaf(rk,ga.z,hg[2]); hg[3]=fmaf(rk,ga.w,hg[3]);
        hg[4]=fmaf(rk,gb.x,hg[4]); hg[5]=fmaf(rk,gb.y,hg[5]); hg[6]=fmaf(rk,gb.z,hg[6]); hg[7]=fmaf(rk,gb.w,hg[7]);
        hg[8]=fmaf(rk,gc.x,hg[8]); hg[9]=fmaf(rk,gc.y,hg[9]);
        hn[0]=fmaf(rk,na.x,hn[0]); hn[1]=fmaf(rk,na.y,hn[1]); hn[2]=fmaf(rk,na.z,hn[2]); hn[3]=fmaf(rk,na.w,hn[3]);
        hn[4]=fmaf(rk,nb.x,hn[4]); hn[5]=fmaf(rk,nb.y,hn[5]); hn[6]=fmaf(rk,nb.z,hn[6]); hn[7]=fmaf(rk,nb.w,hn[7]);
        hn[8]=fmaf(rk,nc.x,hn[8]); hn[9]=fmaf(rk,nc.y,hn[9]);
    }
    float H[NGATE];
    #pragma unroll
    for (int t = 0; t < NGATE; t++) {
        float gv = C*(hg[t] + sv[512+t]) + sv[522+t];
        float nv = C*(hn[t] + sv[532+t]) + sv[542+t];
        H[t] = gv + noise[(long long)e*NGATE + t] * softplusf(nv);
    }
    float m1 = -INFINITY, m2 = -INFINITY;
    #pragma unroll
    for (int t = 0; t < NGATE; t++) {
        float v = H[t];
        if (v > m1) { m2 = m1; m1 = v; } else if (v > m2) { m2 = v; }
    }
    float den = 0.f;
    #pragma unroll
    for (int t = 0; t < NGATE; t++) den += (H[t] >= m2) ? __expf(H[t] - m1) : 0.f;
    float inv = 1.0f / den;
    float g0 = inv;
    float g1 = __expf(m2 - m1) * inv;

    float ex = evec[e*3+0], ey = evec[e*3+1], ez = evec[e*3+2];
    float rn = rsqrtf(ex*ex + ey*ey + ez*ez);
    ex *= rn; ey *= rn; ez *= rn;
    int zd = z[edst[e]];
    int p = atomicAdd(&cursors[esrc[e]], 1);
    wS[p]  = w;
    abS[p] = (bfr(C*g0) >> 16) | bfr(C*g1);
    ggS[p] = (bfr(g0) >> 16)   | bfr(g1);
    xyS[p] = (bfr(ex) >> 16)   | bfr(ey);
    ezdS[p]= bfr(ez) | ((unsigned)j0 << 8) | (unsigned)zd;
}

// ================= main kernel =================
// 256 threads: waves 0-1 = expert 0 (f=tid), waves 2-3 = expert 1 (f=tid-128).
// Each wave-pair keeps only its 52-entry R column set -> all registers resident.
// Tj gathers prefetched 4 deep via scalar aux loads from CSR-ordered ezdS.
#define DST(V,KK) acc = fmaf(V, Rc[KK], acc);
#define DOT12(J) { acc = r0.x*Rc[J]; DST(r0.y,(J)+1) DST(r0.z,(J)+2) DST(r0.w,(J)+3) \
  DST(r1.x,(J)+4) DST(r1.y,(J)+5) DST(r1.z,(J)+6) DST(r1.w,(J)+7) \
  DST(r2.x,(J)+8) DST(r2.y,(J)+9) DST(r2.z,(J)+10) DST(r2.w,(J)+11) }

#define SUB(S, SX, TJ) { \
    int gi = base + i + (S); \
    while (gi == nextEnd) flush(); \
    const float* row = rbuf[i+(S)]; \
    float4 r0 = *(const float4*)&row[0]; \
    float4 r1 = *(const float4*)&row[4]; \
    float4 r2 = *(const float4*)&row[8]; \
    const float* sc = scal[i+(S)]; \
    float4 sA = *(const float4*)&sc[0]; \
    float4 sB = *(const float4*)&sc[4]; \
    float a = pair ? sA.y : sA.x; \
    float g = pair ? sA.w : sA.z; \
    float acc; \
    switch ((SX >> 10) & 15) { \
        case 0: DOT12(0)  break; case 1: DOT12(4)  break; \
        case 2: DOT12(8)  break; case 3: DOT12(12) break; \
        case 4: DOT12(16) break; case 5: DOT12(20) break; \
        case 6: DOT12(24) break; case 7: DOT12(28) break; \
        case 8: DOT12(32) break; case 9: DOT12(36) break; \
        default: DOT12(40) break; } \
    float part = fmaf(a, acc + sV, g * (dtV + (TJ))); \
    accA += part; \
    accX = fmaf(sB.x, part, accX); \
    accY = fmaf(sB.y, part, accY); \
    accZ = fmaf(sB.z, part, accZ); \
    int nx = i + (S) + 4; nx = (nx < nb4) ? nx : 0; \
    SX = (int)ezdS[base + nx]; \
    TJ = TjT[(SX & 0xff)*FOUT + f]; \
}

__global__ __launch_bounds__(256, 4) void k_main(
    const int* __restrict__ z, const int* __restrict__ cursors,
    const float* __restrict__ wS, const unsigned* __restrict__ abS,
    const unsigned* __restrict__ ggS, const unsigned* __restrict__ xyS,
    const unsigned* __restrict__ ezdS,
    const float* __restrict__ R0, const float* __restrict__ R1,
    const float* __restrict__ Ti0, const float* __restrict__ Ti1,
    const float* __restrict__ Tj0, const float* __restrict__ Tj1,
    const float* __restrict__ sv, float* __restrict__ out)
{
    __shared__ float rbuf[256][12];
    __shared__ float scal[256][8];
    __shared__ float stage[4*FOUT];

    const int tid  = threadIdx.x;
    const int pair = tid >> 7;
    const int f    = tid & 127;

    float Rc[52];
    const float* Rtab = pair ? R1 : R0;
    #pragma unroll
    for (int j = 0; j < NRBF; j++) Rc[j] = Rtab[j*FOUT + f];
    Rc[50] = 0.f; Rc[51] = 0.f;
    const float* TiT = pair ? Ti1 : Ti0;
    const float* TjT = pair ? Tj1 : Tj0;
    const float sV = sv[pair*FOUT + f];
    const float dV = sv[256 + pair*FOUT + f];

    const int aBeg = blockIdx.x * APB;
    const int aEnd = aBeg + APB;                 // NATOMS % APB == 0
    const int eBeg = (aBeg == 0) ? 0 : cursors[aBeg-1];
    const int eEnd = cursors[aEnd-1];

    int aCur = aBeg;
    int nextEnd = cursors[aCur];
    float tiNxt = (aCur+1 < aEnd) ? TiT[z[aCur+1]*FOUT + f] : 0.f;
    float dtV = dV + TiT[z[aCur]*FOUT + f];
    float accA=0.f, accX=0.f, accY=0.f, accZ=0.f;

    auto flush = [&]() {
        if (pair) { stage[f]=accA; stage[128+f]=accX; stage[256+f]=accY; stage[384+f]=accZ; }
        __syncthreads();
        if (!pair) {
            out[(size_t)aCur*FOUT + f] = accA + stage[f];
            float* vb = out + (size_t)NATOMS*FOUT + (size_t)aCur*3*FOUT;
            vb[f]        = accX + stage[128+f];
            vb[FOUT+f]   = accY + stage[256+f];
            vb[2*FOUT+f] = accZ + stage[384+f];
        }
        __syncthreads();
        accA=accX=accY=accZ=0.f;
        aCur++;
        if (aCur < aEnd) {
            nextEnd = cursors[aCur];
            dtV = dV + tiNxt;
            tiNxt = (aCur+1 < aEnd) ? TiT[z[aCur+1]*FOUT + f] : 0.f;
        } else {
            nextEnd = 0x7fffffff;
        }
    };

    for (int base = eBeg; base < eEnd; base += 256) {
        const int nb  = min(256, eEnd - base);
        const int nb4 = (nb + 3) & ~3;
        __syncthreads();
        if (tid < nb) {
            int p = base + tid;
            float w = wS[p];
            unsigned ab = abS[p], gg = ggS[p], xy = xyS[p], ezd = ezdS[p];
            int j0 = (ezd >> 8) & 0x3f;
            float rr[12];
            #pragma unroll
            for (int k = 0; k < 12; k++) { float t = w - (j0+k)*RBF_D; rr[k] = exp2f(RBF_C2*t*t); }
            float* row = rbuf[tid];
            *(float4*)&row[0] = make_float4(rr[0],rr[1],rr[2],rr[3]);
            *(float4*)&row[4] = make_float4(rr[4],rr[5],rr[6],rr[7]);
            *(float4*)&row[8] = make_float4(rr[8],rr[9],rr[10],rr[11]);
            float* sc = scal[tid];
            *(float4*)&sc[0] = make_float4(__uint_as_float(ab<<16), __uint_as_float(ab & 0xffff0000u),
                                           __uint_as_float(gg<<16), __uint_as_float(gg & 0xffff0000u));
            *(float4*)&sc[4] = make_float4(__uint_as_float(xy<<16), __uint_as_float(xy & 0xffff0000u),
                                           __uint_as_float(ezd & 0xffff0000u), 0.f);
        } else {
            float* row = rbuf[tid];
            *(float4*)&row[0] = make_float4(0,0,0,0);
            *(float4*)&row[4] = make_float4(0,0,0,0);
            *(float4*)&row[8] = make_float4(0,0,0,0);
            float* sc = scal[tid];
            *(float4*)&sc[0] = make_float4(0,0,0,0);
            *(float4*)&sc[4] = make_float4(0,0,0,0);
        }
        __syncthreads();

        // scalar aux + Tj prefetch, 4 deep (ezdS has >=64 ints of alloc padding)
        int sx0 = (int)ezdS[base+0];
        int sx1 = (int)ezdS[base+1];
        int sx2 = (int)ezdS[base+2];
        int sx3 = (int)ezdS[base+3];
        float tj0 = TjT[(sx0 & 0xff)*FOUT + f];
        float tj1 = TjT[(sx1 & 0xff)*FOUT + f];
        float tj2 = TjT[(sx2 & 0xff)*FOUT + f];
        float tj3 = TjT[(sx3 & 0xff)*FOUT + f];

        for (int i = 0; i < nb4; i += 4) {
            SUB(0, sx0, tj0)
            SUB(1, sx1, tj1)
            SUB(2, sx2, tj2)
            SUB(3, sx3, tj3)
        }
    }
    while (aCur < aEnd) flush();
}

extern "C" void kernel_launch(void* const* d_in, const int* in_sizes, int n_in,
                              void* d_out, int out_size, void* d_ws, size_t ws_size,
                              hipStream_t stream)
{
    const int*   z    = (const int*)d_in[0];
    const int*   ei   = (const int*)d_in[3];
    const int*   esrc = ei;
    const int*   edst = ei + NEDGES;
    const float* ew   = (const float*)d_in[4];
    const float* evec = (const float*)d_in[5];
    const float* nz   = (const float*)d_in[6];
    const float* emb  = (const float*)d_in[7];
    const float* Wd   = (const float*)d_in[8];
    const float* bd   = (const float*)d_in[9];
    const float* Wdt  = (const float*)d_in[10];
    const float* bdt  = (const float*)d_in[11];
    const float* Wai  = (const float*)d_in[12];
    const float* bai  = (const float*)d_in[13];
    const float* Waj  = (const float*)d_in[14];
    const float* baj  = (const float*)d_in[15];
    const float* Wgam = (const float*)d_in[16];
    const float* bgam = (const float*)d_in[17];
    const float* Wg   = (const float*)d_in[18];
    const float* Wn   = (const float*)d_in[19];
    const float* Wexp = (const float*)d_in[20];
    const float* bexp = (const float*)d_in[21];
    float* out = (float*)d_out;

    char* w = (char*)d_ws;
    auto alloc = [&](size_t bytes) -> void* {
        void* p = (void*)w;
        w += (bytes + 255) & ~(size_t)255;
        return p;
    };
    int*   counts  = (int*)alloc(NATOMS * 4);
    int*   cursors = (int*)alloc(NATOMS * 4);
    float* R0  = (float*)alloc(NRBF*FOUT*4);
    float* R1  = (float*)alloc(NRBF*FOUT*4);
    float* Qg  = (float*)alloc(52*12*4);
    float* Qn  = (float*)alloc(52*12*4);
    float* Ti0 = (float*)alloc(100*FOUT*4);
    float* Ti1 = (float*)alloc(100*FOUT*4);
    float* Tj0 = (float*)alloc(100*FOUT*4);
    float* Tj1 = (float*)alloc(100*FOUT*4);
    float* sv  = (float*)alloc(552*4);
    float*    wS   = (float*)alloc((size_t)NEDGES*4);
    unsigned* abS  = (unsigned*)alloc((size_t)NEDGES*4);
    unsigned* ggS  = (unsigned*)alloc((size_t)NEDGES*4);
    unsigned* xyS  = (unsigned*)alloc((size_t)NEDGES*4);
    unsigned* ezdS = (unsigned*)alloc((size_t)NEDGES*4 + 256);  // +pad: k_main over-reads <=+3

    hipMemsetAsync(counts, 0, NATOMS*4, stream);

    {
        int grid = 252 + (NEDGES + 255) / 256;
        k_tab<<<grid, 256, 0, stream>>>(emb, Wai, bai, Waj, baj, Wgam, Wexp, bexp,
                                        Wd, Wdt, bd, bdt, bgam, Wg, Wn,
                                        esrc, counts,
                                        Ti0, Ti1, Tj0, Tj1, R0, R1, Qg, Qn, sv);
    }
    k_scan<<<1, 256, 0, stream>>>(counts, cursors);
    {
        int grid = (NEDGES + 255) / 256;
        k_edge<<<grid, 256, 0, stream>>>(z, esrc, edst, ew, evec, nz,
                                         Qg, Qn, sv, cursors,
                                         wS, abS, ggS, xyS, ezdS);
    }
    {
        int grid = NATOMS / APB;   // 2500
        k_main<<<grid, 256, 0, stream>>>(z, cursors, wS, abS, ggS, xyS, ezdS,
                                         R0, R1, Ti0, Ti1, Tj0, Tj1, sv, out);
    }
}